// Round 9
// baseline (869.199 us; speedup 1.0000x reference)
//
#include <hip/hip_runtime.h>
#include <stdint.h>

#define HID 256

typedef __attribute__((ext_vector_type(8))) short bf16x8;   // 8 bf16 (4 VGPRs)
typedef __attribute__((ext_vector_type(4))) float f32x4;
typedef __attribute__((ext_vector_type(2))) float f32x2;

__device__ __forceinline__ float bf2f(unsigned short u) {
    union { unsigned int i; float f; } v; v.i = ((unsigned int)u) << 16; return v.f;
}
__device__ __forceinline__ unsigned short f2bf(float f) {
    union { float f; unsigned int i; } v; v.f = f;
    unsigned int r = (v.i + 0x7fffu + ((v.i >> 16) & 1u)) >> 16;
    return (unsigned short)r;
}
// ---- software fp8 e4m3fn fallbacks (exact w.r.t. the hw path) ----
__device__ __forceinline__ float fp82f_sw(unsigned char b) {
    unsigned int s = (unsigned int)(b & 0x80) << 24;
    int e = (b >> 3) & 0xF;
    int m = b & 7;
    float v;
    if (e) v = __uint_as_float(((unsigned int)(e + 120) << 23) | ((unsigned int)m << 20));
    else   v = (float)m * 0.001953125f;
    return __uint_as_float(__float_as_uint(v) | s);
}
__device__ __forceinline__ unsigned char f2fp8_sw(float x) {
    unsigned int bits = __float_as_uint(x);
    unsigned char s = (unsigned char)((bits >> 24) & 0x80);
    float ax = fabsf(x);
    if (!(ax >= 0.001953125f)) {
        int n = (int)rintf(ax * 512.f);
        return s | (unsigned char)n;
    }
    if (ax >= 448.f) return s | 0x7E;
    int ex; float mant = frexpf(ax, &ex);
    int e = ex + 6;
    if (e >= 1) {
        int q = (int)rintf(mant * 16.f);
        if (q == 16) { q = 8; ++e; }
        if (e > 15 || (e == 15 && q > 14)) return s | 0x7E;
        return s | (unsigned char)((e << 3) | (q - 8));
    } else {
        int n = (int)rintf(ax * 512.f);
        if (n >= 8) return s | 0x08;
        return s | (unsigned char)n;
    }
}
// ---- hardware fp8 conversion (gfx950: OCP e4m3fn) ----
__device__ __forceinline__ unsigned char f2fp8(float x) {
#if __has_builtin(__builtin_amdgcn_cvt_pk_fp8_f32)
    return (unsigned char)(__builtin_amdgcn_cvt_pk_fp8_f32(x, x, 0, false) & 0xff);
#else
    return f2fp8_sw(x);
#endif
}
__device__ __forceinline__ f32x4 fp8x4_to_f32(unsigned int u) {
#if __has_builtin(__builtin_amdgcn_cvt_pk_f32_fp8)
    f32x2 a = __builtin_amdgcn_cvt_pk_f32_fp8(u, false);
    f32x2 b = __builtin_amdgcn_cvt_pk_f32_fp8(u, true);
    f32x4 r; r[0] = a.x; r[1] = a.y; r[2] = b.x; r[3] = b.y;
    return r;
#else
    f32x4 r;
    #pragma unroll
    for (int q = 0; q < 4; ++q) r[q] = fp82f_sw((u >> (8 * q)) & 0xff);
    return r;
#endif
}
// 8 fp8 bytes -> 8 bf16 (exact: every e4m3fn value is representable in bf16)
__device__ __forceinline__ bf16x8 fp8x8_to_bf16x8(uint2 raw) {
#if __has_builtin(__builtin_amdgcn_cvt_pk_f32_fp8)
    f32x2 p0 = __builtin_amdgcn_cvt_pk_f32_fp8(raw.x, false);
    f32x2 p1 = __builtin_amdgcn_cvt_pk_f32_fp8(raw.x, true);
    f32x2 p2 = __builtin_amdgcn_cvt_pk_f32_fp8(raw.y, false);
    f32x2 p3 = __builtin_amdgcn_cvt_pk_f32_fp8(raw.y, true);
    union { unsigned int u[4]; bf16x8 v; } cv;
    cv.u[0] = (__float_as_uint(p0.x) >> 16) | (__float_as_uint(p0.y) & 0xffff0000u);
    cv.u[1] = (__float_as_uint(p1.x) >> 16) | (__float_as_uint(p1.y) & 0xffff0000u);
    cv.u[2] = (__float_as_uint(p2.x) >> 16) | (__float_as_uint(p2.y) & 0xffff0000u);
    cv.u[3] = (__float_as_uint(p3.x) >> 16) | (__float_as_uint(p3.y) & 0xffff0000u);
    return cv.v;
#else
    union { unsigned short u[8]; bf16x8 v; } cv;
    #pragma unroll
    for (int q = 0; q < 4; ++q) cv.u[q]     = f2bf(fp82f_sw((raw.x >> (8 * q)) & 0xff));
    #pragma unroll
    for (int q = 0; q < 4; ++q) cv.u[4 + q] = f2bf(fp82f_sw((raw.y >> (8 * q)) & 0xff));
    return cv.v;
#endif
}

// async global->LDS, 16B per lane; LDS dest = wave-uniform base + lane*16
__device__ __forceinline__ void llds16(const void* g, void* l) {
    __builtin_amdgcn_global_load_lds(
        (const __attribute__((address_space(1))) void*)g,
        (__attribute__((address_space(3))) void*)l, 16, 0, 0);
}

// ---------------- utility / prep kernels ----------------

__global__ void k_zero_f(float* __restrict__ p, size_t n) {
    size_t i = (size_t)blockIdx.x * 256 + threadIdx.x;
    if (i < n) p[i] = 0.f;
}
__global__ void k_diag(float* __restrict__ out, float v) {
    if (blockIdx.x == 0 && threadIdx.x == 0) out[0] = v;
}

// one-shot init: zero cnt_lg[E], cnt_nd[N], cnt_t[N], gcnt[G], cursors[4]; gstart[G]=N
__global__ void k_init(int* __restrict__ cnt_lg, int E,
                       int* __restrict__ cnt_nd, int* __restrict__ cnt_t, int N,
                       int* __restrict__ gcnt, int* __restrict__ gstart, int G,
                       int* __restrict__ cur) {
    int i = blockIdx.x * 256 + threadIdx.x;
    if (i < E) cnt_lg[i] = 0;
    if (i < N) { cnt_nd[i] = 0; cnt_t[i] = 0; }
    if (i < G) { gcnt[i] = 0; gstart[i] = N; }
    if (i < 4) cur[i] = 0;
}

// CSR pass 1: count degrees (atomics only, no scattered payload -> no write amp)
__global__ void k_count(const int* __restrict__ lg_dst, int* __restrict__ cnt_lg, int L,
                        const int* __restrict__ edst, int* __restrict__ cnt_nd, int E,
                        const int* __restrict__ tgt, int* __restrict__ cnt_t, int T,
                        const int* __restrict__ gid, int* __restrict__ gstart,
                        int* __restrict__ gcnt, int N) {
    int i = blockIdx.x * 256 + threadIdx.x;
    if (i < L) atomicAdd(&cnt_lg[lg_dst[i]], 1);
    if (i < E) atomicAdd(&cnt_nd[edst[i]], 1);
    if (i < T) atomicAdd(&cnt_t[tgt[i]], 1);
    if (i < N) { int g = gid[i]; atomicAdd(&gcnt[g], 1); atomicMin(&gstart[g], i); }
}

// CSR pass 2: offsets via block-aggregated cursor allocation (ONE global atomic
// per block per array; row order need not be monotonic — only packed).
// Resets cnt to 0 for reuse as the placement cursor in pass 3.
__global__ void k_off(int* __restrict__ cnt_lg, int* __restrict__ off_lg, int E,
                      int* __restrict__ cnt_nd, int* __restrict__ off_nd,
                      int* __restrict__ cnt_t, int* __restrict__ off_t, int N,
                      int* __restrict__ cur) {
    __shared__ int ws[4];
    __shared__ int wb[4];
    const int tid = threadIdx.x, lane = tid & 63, wv = tid >> 6;
    const int i = blockIdx.x * 256 + tid;

    auto blk_alloc = [&](int c, int* cursor) -> int {
        int x = c;
        #pragma unroll
        for (int s = 1; s < 64; s <<= 1) {
            int y = __shfl_up(x, s, 64);
            if (lane >= s) x += y;
        }
        int pre = x - c;                 // exclusive prefix within wave
        if (lane == 63) ws[wv] = x;      // wave total
        __syncthreads();
        if (tid == 0) {
            int b0 = ws[0], b1 = ws[1], b2 = ws[2], b3 = ws[3];
            int base = atomicAdd(cursor, b0 + b1 + b2 + b3);
            wb[0] = base; wb[1] = base + b0; wb[2] = base + b0 + b1; wb[3] = base + b0 + b1 + b2;
        }
        __syncthreads();
        int r = wb[wv] + pre;
        __syncthreads();                 // ws/wb reused by next call
        return r;
    };

    int c1 = (i < E) ? cnt_lg[i] : 0;
    int o1 = blk_alloc(c1, &cur[0]);
    if (i < E) { off_lg[i] = o1; cnt_lg[i] = 0; }

    int c2 = (i < N) ? cnt_nd[i] : 0;
    int o2 = blk_alloc(c2, &cur[1]);
    if (i < N) { off_nd[i] = o2; cnt_nd[i] = 0; }

    int c3 = (i < N) ? cnt_t[i] : 0;
    int o3 = blk_alloc(c3, &cur[2]);
    if (i < N) { off_t[i] = o3; cnt_t[i] = 0; }
}

// CSR pass 3: place entries into PACKED arrays (dense lines -> writeback = payload).
// Restores cnt to the exact degree as a side effect.
__global__ void k_place(const int* __restrict__ lg_dst, const int* __restrict__ lg_src,
                        int* __restrict__ cnt_lg, const int* __restrict__ off_lg,
                        int* __restrict__ csr_lg, int L,
                        const int* __restrict__ edst, int* __restrict__ cnt_nd,
                        const int* __restrict__ off_nd, int* __restrict__ csr_nd, int E,
                        const int* __restrict__ tgt, int* __restrict__ cnt_t,
                        const int* __restrict__ off_t, int* __restrict__ csr_t, int T) {
    int i = blockIdx.x * 256 + threadIdx.x;
    if (i < L) { int d = lg_dst[i]; int p = atomicAdd(&cnt_lg[d], 1); csr_lg[off_lg[d] + p] = lg_src[i]; }
    if (i < E) { int d = edst[i];   int p = atomicAdd(&cnt_nd[d], 1); csr_nd[off_nd[d] + p] = i; }
    if (i < T) { int d = tgt[i];    int p = atomicAdd(&cnt_t[d], 1);  csr_t[off_t[d] + p]  = i; }
}

// alpha[v] = fp8( sum_{t in csr_t[v]} tree_mess[t] )   (one wave per node, 4 cols/lane)
__global__ void k_alpha(const float* __restrict__ tm, const int* __restrict__ cnt,
                        const int* __restrict__ off, const int* __restrict__ csr,
                        unsigned char* __restrict__ alpha, int N) {
    int wave = threadIdx.x >> 6, lane = threadIdx.x & 63;
    int v = blockIdx.x * 4 + wave;
    if (v >= N) return;
    int d = cnt[v];
    int st = off[v];
    f32x4 s = {0.f, 0.f, 0.f, 0.f};
    for (int t = 0; t < d; ++t) {
        int r = csr[st + t];
        f32x4 x = *(const f32x4*)(tm + (size_t)r * HID + lane * 4);
        #pragma unroll
        for (int k = 0; k < 4; ++k) s[k] += x[k];
    }
    union { unsigned char b[4]; unsigned int u; } ov;
    #pragma unroll
    for (int k = 0; k < 4; ++k) ov.b[k] = f2fp8(s[k]);
    *(unsigned int*)(alpha + (size_t)v * HID + lane * 4) = ov.u;
}

// merged weight builders (bf16, transposed+padded):
// Wt_i[n][k] (256x64): k<40 -> W_i[k][n]; Wt_hi[n][k] (256x320): k<256 W_h, k-256<40 W_i;
// Wt_o[n][k] (256x320): k<256 -> W_o[35+k][n], k-256<35 -> W_o[k-256][n]
__global__ void k_wt(const float* __restrict__ Wi, const float* __restrict__ Wh,
                     const float* __restrict__ Wo,
                     unsigned short* __restrict__ Wt_i, unsigned short* __restrict__ Wt_hi,
                     unsigned short* __restrict__ Wt_o) {
    int i = blockIdx.x * 256 + threadIdx.x;
    if (i < 256 * 64) {
        int n = i >> 6, k = i & 63;
        Wt_i[i] = f2bf((k < 40) ? Wi[k * HID + n] : 0.f);
    }
    if (i < 256 * 320) {
        int n = i / 320, k = i % 320;
        float v, u;
        if (k < 256) v = Wh[(size_t)k * HID + n];
        else if (k < 296) v = Wi[(size_t)(k - 256) * HID + n];
        else v = 0.f;
        Wt_hi[i] = f2bf(v);
        if (k < 256) u = Wo[(size_t)(35 + k) * HID + n];
        else if (k < 291) u = Wo[(size_t)(k - 256) * HID + n];
        else u = 0.f;
        Wt_o[i] = f2bf(u);
    }
}

// A1[e][0..63] fp8: k<35 node_x[src][k], 35..39 bond_x[e][k-35], else 0
// 4 threads/edge, 16B store each.
__global__ void k_a1(const float* __restrict__ nx, const float* __restrict__ bx,
                     const int* __restrict__ esrc, unsigned char* __restrict__ A1, int E) {
    int i = blockIdx.x * 256 + threadIdx.x;
    int e = i >> 2, q = i & 3;
    if (e >= E) return;
    int src = esrc[e];
    const float* row = nx + (size_t)src * 35;
    int base = q * 16;
    union { unsigned char b[16]; uint4 u; } ov;
    #pragma unroll
    for (int k = 0; k < 16; ++k) {
        int col = base + k;
        float v = 0.f;
        if (col < 35) v = row[col];
        else if (col < 40) v = bx[(size_t)e * 5 + (col - 35)];
        ov.b[k] = f2fp8(v);
    }
    *(uint4*)(A1 + (size_t)e * 64 + base) = ov.u;
}

// X1[v][0..63] fp8: k<35 node_x[v][k], else 0   (4 threads/node)
__global__ void k_x1(const float* __restrict__ nx, unsigned char* __restrict__ X1, int N) {
    int i = blockIdx.x * 256 + threadIdx.x;
    int v = i >> 2, q = i & 3;
    if (v >= N) return;
    const float* row = nx + (size_t)v * 35;
    int base = q * 16;
    union { unsigned char b[16]; uint4 u; } ov;
    #pragma unroll
    for (int k = 0; k < 16; ++k) {
        int col = base + k;
        ov.b[k] = f2fp8((col < 35) ? row[col] : 0.f);
    }
    *(uint4*)(X1 + (size_t)v * 64 + base) = ov.u;
}

// ---------------- split-A GEMM, m97 staging, 128x256 tile (R2 proven: ~80us) ----------------
// C[M,256] = [Ap (K1 cols) | Aq (KTOT-K1 cols)] @ B[256][KTOT]^T   (B bf16)
// BM=128, BN=256 (grid.y==1); 4 waves 2x2; per-wave 64x128; acc[4][8] f32x4.
// NOTE on occupancy (R7 lesson): gfx950 has a UNIFIED VGPR/AGPR file. This
// kernel's true register footprint is ~112 arch + 128 acc ≈ 240 regs/thread,
// so 2 waves/SIMD is the register-bound occupancy. __launch_bounds__(256,2)
// is the correct declaration; (256,4) caps the unified budget at 128 and
// spills the accumulators to scratch (405us, 944MB scratch writes — R7).
// Staging: global_load_lds width=16; source-chunk XOR swizzle both-sides
// (ck ^ (row&7) for 128B rows, ^(row&3) for 64B fp8 rows; same XOR on ds_read).
// fp8 A stays fp8 in LDS; converted to bf16 at fragment read.
// EPI 0: relu(C); EPI 1: relu(C + bias[col]).  OUTF8: store fp8 else bf16.
template<int K1, int KTOT, int EPI, bool PF8, bool QF8, bool OUTF8>
__global__ __launch_bounds__(256, 2)
void gemm4(const void* __restrict__ Ap, int lda1,
           const void* __restrict__ Aq, int lda2,
           const unsigned short* __restrict__ B, int M,
           void* __restrict__ out, const float* __restrict__ bias)
{
    constexpr int NKC = KTOT / 64;
    constexpr bool ABF = (K1 > 0 && !PF8) || (KTOT > K1 && !QF8);  // any bf16 A part
    __shared__ unsigned char Als[ABF ? 128 * 128 : 128 * 64];
    __shared__ unsigned char Bls[256 * 128];   // bf16 [256][128B]
    const int tid  = threadIdx.x;
    const int lane = tid & 63;
    const int wid  = tid >> 6;
    const int wm = wid & 1, wn = wid >> 1;
    const int row0 = blockIdx.x * 128;
    const int l15  = lane & 15;
    const int quad = lane >> 4;

    f32x4 acc[4][8] = {};

    // staging lane coords
    const int sA8_r = lane >> 2, sA8_c = lane & 3;   // fp8 A: 16 rows/issue, 4 chunks/row
    const int s16_r = lane >> 3, s16_c = lane & 7;   // 128B rows: 8 rows/issue, 8 chunks/row

    #pragma unroll
    for (int kc = 0; kc < NKC; ++kc) {
        const bool pPart = (kc * 64 < K1);
        const void* As = pPart ? Ap : Aq;
        const int  lda  = pPart ? lda1 : lda2;     // in elements of the A dtype
        const int  kofs = pPart ? kc * 64 : kc * 64 - K1;
        const bool f8   = pPart ? PF8 : QF8;

        // ---- stage A tile (async) ----
        if (f8) {
            #pragma unroll
            for (int t = 0; t < 2; ++t) {
                int r = wid * 32 + t * 16 + sA8_r;            // 0..127
                int ar = row0 + r; if (ar > M - 1) ar = M - 1;
                int ck = sA8_c ^ (r & 3);                      // source chunk (16B units)
                const unsigned char* g = (const unsigned char*)As + (size_t)ar * lda + kofs + ck * 16;
                llds16(g, &Als[(wid * 32 + t * 16) * 64]);
            }
        } else {
            #pragma unroll
            for (int t = 0; t < 4; ++t) {
                int r = wid * 32 + t * 8 + s16_r;
                int ar = row0 + r; if (ar > M - 1) ar = M - 1;
                int ck = s16_c ^ (r & 7);
                const unsigned char* g = (const unsigned char*)As + ((size_t)ar * lda + kofs) * 2 + ck * 16;
                llds16(g, &Als[(wid * 32 + t * 8) * 128]);
            }
        }
        // ---- stage B tile (async): all 256 rows of B[256][KTOT] ----
        #pragma unroll
        for (int t = 0; t < 8; ++t) {
            int r = wid * 64 + t * 8 + s16_r;                  // 0..255
            int ck = s16_c ^ (r & 7);
            const unsigned char* g = (const unsigned char*)B + ((size_t)r * KTOT + kc * 64) * 2 + ck * 16;
            llds16(g, &Bls[(wid * 64 + t * 8) * 128]);
        }
        __syncthreads();   // vmcnt drain before s_barrier -> tile resident

        // ---- MFMA phase ----
        #pragma unroll
        for (int kk = 0; kk < 64; kk += 32) {
            bf16x8 af[4];
            #pragma unroll
            for (int i = 0; i < 4; ++i) {
                int arow = wm * 64 + i * 16 + l15;
                if (f8) {
                    int ck = (kk >> 4) + (quad >> 1);          // 0..3
                    uint2 raw = *(const uint2*)&Als[arow * 64 + ((ck ^ (arow & 3)) << 4) + ((quad & 1) << 3)];
                    af[i] = fp8x8_to_bf16x8(raw);
                } else {
                    int ck = (kk >> 3) + quad;                 // 0..7
                    af[i] = *(const bf16x8*)&Als[arow * 128 + ((ck ^ (arow & 7)) << 4)];
                }
            }
            #pragma unroll
            for (int j = 0; j < 8; ++j) {
                int brow = wn * 128 + j * 16 + l15;
                int ck = (kk >> 3) + quad;
                bf16x8 bfr = *(const bf16x8*)&Bls[brow * 128 + ((ck ^ (brow & 7)) << 4)];
                #pragma unroll
                for (int i = 0; i < 4; ++i)
                    acc[i][j] = __builtin_amdgcn_mfma_f32_16x16x32_bf16(af[i], bfr, acc[i][j], 0, 0, 0);
            }
        }
        if (kc + 1 < NKC) __syncthreads();   // protect LDS before next stage
    }

    // epilogue: C/D layout col = lane&15, row = quad*4 + reg
    #pragma unroll
    for (int i = 0; i < 4; ++i) {
        int rbase = row0 + wm * 64 + i * 16 + quad * 4;
        #pragma unroll
        for (int r = 0; r < 4; ++r) {
            int row = rbase + r;
            if (row >= M) continue;
            #pragma unroll
            for (int j = 0; j < 8; ++j) {
                int col = wn * 128 + j * 16 + l15;
                float v = acc[i][j][r];
                if (EPI == 1) v += bias[col];
                v = v > 0.f ? v : 0.f;
                if (OUTF8) ((unsigned char*)out)[(size_t)row * HID + col] = f2fp8(v);
                else       ((unsigned short*)out)[(size_t)row * HID + col] = f2bf(v);
            }
        }
    }
}

// ---------------- gather kernels (CSR inputs) ----------------

// accum[e] = alpha[esrc[e]] + sum_{j in csr_lg row e} msg[j]   (fp8 out)
// 4 edges per wave: 16 lanes x 16B per edge row (uint4), high-occupancy TLP.
__global__ void k_accum(const unsigned char* __restrict__ msg, const unsigned char* __restrict__ alpha,
                        const int* __restrict__ esrc, const int* __restrict__ cnt,
                        const int* __restrict__ off, const int* __restrict__ csr,
                        unsigned char* __restrict__ accum, int E)
{
    int tid  = threadIdx.x;
    int lane = tid & 63, wave = tid >> 6;
    int sub  = lane >> 4;            // 0..3: which edge in this wave
    int sl   = lane & 15;
    int e = blockIdx.x * 16 + wave * 4 + sub;
    if (e >= E) return;
    int c = sl * 16;
    int src = esrc[e];
    int d = cnt[e];
    const int* cs = csr + off[e];
    uint4 au = *(const uint4*)(alpha + (size_t)src * HID + c);
    f32x4 s0 = fp8x4_to_f32(au.x);
    f32x4 s1 = fp8x4_to_f32(au.y);
    f32x4 s2 = fp8x4_to_f32(au.z);
    f32x4 s3 = fp8x4_to_f32(au.w);
    for (int base = 0; base < d; base += 4) {
        int rem = d - base;
        int i0 = cs[base];
        int i1 = (rem > 1) ? cs[base + 1] : i0;
        int i2 = (rem > 2) ? cs[base + 2] : i0;
        int i3 = (rem > 3) ? cs[base + 3] : i0;
        uint4 m0 = *(const uint4*)(msg + (size_t)i0 * HID + c);
        uint4 m1 = *(const uint4*)(msg + (size_t)i1 * HID + c);
        uint4 m2 = *(const uint4*)(msg + (size_t)i2 * HID + c);
        uint4 m3 = *(const uint4*)(msg + (size_t)i3 * HID + c);
        {   f32x4 a0 = fp8x4_to_f32(m0.x), a1 = fp8x4_to_f32(m0.y), a2 = fp8x4_to_f32(m0.z), a3 = fp8x4_to_f32(m0.w);
            #pragma unroll
            for (int k = 0; k < 4; ++k) { s0[k] += a0[k]; s1[k] += a1[k]; s2[k] += a2[k]; s3[k] += a3[k]; } }
        if (rem > 1) { f32x4 a0 = fp8x4_to_f32(m1.x), a1 = fp8x4_to_f32(m1.y), a2 = fp8x4_to_f32(m1.z), a3 = fp8x4_to_f32(m1.w);
            #pragma unroll
            for (int k = 0; k < 4; ++k) { s0[k] += a0[k]; s1[k] += a1[k]; s2[k] += a2[k]; s3[k] += a3[k]; } }
        if (rem > 2) { f32x4 a0 = fp8x4_to_f32(m2.x), a1 = fp8x4_to_f32(m2.y), a2 = fp8x4_to_f32(m2.z), a3 = fp8x4_to_f32(m2.w);
            #pragma unroll
            for (int k = 0; k < 4; ++k) { s0[k] += a0[k]; s1[k] += a1[k]; s2[k] += a2[k]; s3[k] += a3[k]; } }
        if (rem > 3) { f32x4 a0 = fp8x4_to_f32(m3.x), a1 = fp8x4_to_f32(m3.y), a2 = fp8x4_to_f32(m3.z), a3 = fp8x4_to_f32(m3.w);
            #pragma unroll
            for (int k = 0; k < 4; ++k) { s0[k] += a0[k]; s1[k] += a1[k]; s2[k] += a2[k]; s3[k] += a3[k]; } }
    }
    union { unsigned char b[16]; uint4 u; } ov;
    #pragma unroll
    for (int k = 0; k < 4; ++k) {
        ov.b[k]      = f2fp8(s0[k]);
        ov.b[4 + k]  = f2fp8(s1[k]);
        ov.b[8 + k]  = f2fp8(s2[k]);
        ov.b[12 + k] = f2fp8(s3[k]);
    }
    *(uint4*)(accum + (size_t)e * HID + c) = ov.u;
}

// Mb[v] = alpha[v] + sum_{e in csr_nd row v} msg[e]   (bf16 out)
// 4 nodes/wave: 16 lanes x 16 cols each (16B fp8 in, 32B bf16 out).
__global__ void k_mpa(const unsigned char* __restrict__ msg, const unsigned char* __restrict__ alpha,
                      const int* __restrict__ cnt, const int* __restrict__ off,
                      const int* __restrict__ csr, unsigned short* __restrict__ Mb, int N)
{
    int tid  = threadIdx.x;
    int lane = tid & 63, wave = tid >> 6;
    int sub  = lane >> 4;
    int sl   = lane & 15;
    int v = blockIdx.x * 16 + wave * 4 + sub;
    if (v >= N) return;
    int c = sl * 16;
    int d = cnt[v];
    const int* cs = csr + off[v];
    uint4 au = *(const uint4*)(alpha + (size_t)v * HID + c);
    f32x4 s0 = fp8x4_to_f32(au.x);
    f32x4 s1 = fp8x4_to_f32(au.y);
    f32x4 s2 = fp8x4_to_f32(au.z);
    f32x4 s3 = fp8x4_to_f32(au.w);
    for (int base = 0; base < d; base += 4) {
        int rem = d - base;
        int i0 = cs[base];
        int i1 = (rem > 1) ? cs[base + 1] : i0;
        int i2 = (rem > 2) ? cs[base + 2] : i0;
        int i3 = (rem > 3) ? cs[base + 3] : i0;
        uint4 m0 = *(const uint4*)(msg + (size_t)i0 * HID + c);
        uint4 m1 = *(const uint4*)(msg + (size_t)i1 * HID + c);
        uint4 m2 = *(const uint4*)(msg + (size_t)i2 * HID + c);
        uint4 m3 = *(const uint4*)(msg + (size_t)i3 * HID + c);
        {   f32x4 a0 = fp8x4_to_f32(m0.x), a1 = fp8x4_to_f32(m0.y), a2 = fp8x4_to_f32(m0.z), a3 = fp8x4_to_f32(m0.w);
            #pragma unroll
            for (int k = 0; k < 4; ++k) { s0[k] += a0[k]; s1[k] += a1[k]; s2[k] += a2[k]; s3[k] += a3[k]; } }
        if (rem > 1) { f32x4 a0 = fp8x4_to_f32(m1.x), a1 = fp8x4_to_f32(m1.y), a2 = fp8x4_to_f32(m1.z), a3 = fp8x4_to_f32(m1.w);
            #pragma unroll
            for (int k = 0; k < 4; ++k) { s0[k] += a0[k]; s1[k] += a1[k]; s2[k] += a2[k]; s3[k] += a3[k]; } }
        if (rem > 2) { f32x4 a0 = fp8x4_to_f32(m2.x), a1 = fp8x4_to_f32(m2.y), a2 = fp8x4_to_f32(m2.z), a3 = fp8x4_to_f32(m2.w);
            #pragma unroll
            for (int k = 0; k < 4; ++k) { s0[k] += a0[k]; s1[k] += a1[k]; s2[k] += a2[k]; s3[k] += a3[k]; } }
        if (rem > 3) { f32x4 a0 = fp8x4_to_f32(m3.x), a1 = fp8x4_to_f32(m3.y), a2 = fp8x4_to_f32(m3.z), a3 = fp8x4_to_f32(m3.w);
            #pragma unroll
            for (int k = 0; k < 4; ++k) { s0[k] += a0[k]; s1[k] += a1[k]; s2[k] += a2[k]; s3[k] += a3[k]; } }
    }
    union { unsigned short h[8]; uint4 u; } o1, o2;
    #pragma unroll
    for (int k = 0; k < 4; ++k) {
        o1.h[k] = f2bf(s0[k]); o1.h[4 + k] = f2bf(s1[k]);
        o2.h[k] = f2bf(s2[k]); o2.h[4 + k] = f2bf(s3[k]);
    }
    *(uint4*)(Mb + (size_t)v * HID + c)     = o1.u;
    *(uint4*)(Mb + (size_t)v * HID + c + 8) = o2.u;
}

// per-graph mean (graph_ids sorted -> contiguous rows), 4-way unrolled for ILP
__global__ void k_gmean(const unsigned short* __restrict__ h, const int* __restrict__ gstart,
                        const int* __restrict__ gcnt, float* __restrict__ out, int G) {
    int g = blockIdx.x;
    int c = threadIdx.x;
    int st = gstart[g], n = gcnt[g];
    float s0 = 0.f, s1 = 0.f, s2 = 0.f, s3 = 0.f;
    int r = 0;
    for (; r + 4 <= n; r += 4) {
        s0 += bf2f(h[(size_t)(st + r) * HID + c]);
        s1 += bf2f(h[(size_t)(st + r + 1) * HID + c]);
        s2 += bf2f(h[(size_t)(st + r + 2) * HID + c]);
        s3 += bf2f(h[(size_t)(st + r + 3) * HID + c]);
    }
    float s = (s0 + s1) + (s2 + s3);
    for (; r < n; ++r) s += bf2f(h[(size_t)(st + r) * HID + c]);
    out[(size_t)g * HID + c] = (n > 0) ? s / (float)n : 0.f;
}

// ---------------- launch ----------------
extern "C" void kernel_launch(void* const* d_in, const int* in_sizes, int n_in,
                              void* d_out, int out_size, void* d_ws, size_t ws_size,
                              hipStream_t stream)
{
    const float* node_x    = (const float*)d_in[0];
    const float* bond_x    = (const float*)d_in[1];
    const float* tree_mess = (const float*)d_in[2];
    const float* W_i       = (const float*)d_in[3];
    const float* W_h       = (const float*)d_in[4];
    const float* W_o       = (const float*)d_in[5];
    const float* b_o       = (const float*)d_in[6];
    const int* edge_src    = (const int*)d_in[7];
    const int* edge_dst    = (const int*)d_in[8];
    const int* lg_src      = (const int*)d_in[9];
    const int* lg_dst      = (const int*)d_in[10];
    const int* tgt_nodes   = (const int*)d_in[11];
    const int* graph_ids   = (const int*)d_in[12];

    const int N = in_sizes[0] / 35;
    const int E = in_sizes[1] / 5;
    const int T = in_sizes[2] / HID;
    const int L = in_sizes[9];
    const int G = out_size / HID;

    auto rup = [](size_t b) { return (b + 255) & ~(size_t)255; };
    const size_t szAcc = (size_t)E * HID;        // accum fp8
    const size_t szMsg = (size_t)E * HID;        // msg fp8
    const size_t szMbN = (size_t)N * HID * 2;    // Mb/h bf16
    const size_t R_acc = rup(szAcc > szMbN ? szAcc : szMbN);
    const size_t R_msg = rup(szMsg > szMbN ? szMsg : szMbN);
    const size_t R_al  = rup((size_t)N * HID);   // alpha fp8
    const size_t R_a1  = rup((size_t)E * 64);    // A1/X1 fp8
    const size_t need = R_acc + R_msg + R_al + R_a1
        + rup(256 * 64 * 2) + rup((size_t)256 * 320 * 2) * 2
        + rup((size_t)E * 4) + rup((size_t)E * 4) + rup((size_t)L * 4)   // cnt/off/csr lg
        + rup((size_t)N * 4) + rup((size_t)N * 4) + rup((size_t)E * 4)   // cnt/off/csr nd
        + rup((size_t)N * 4) + rup((size_t)N * 4) + rup((size_t)T * 4)   // cnt/off/csr t
        + rup((size_t)G * 4) * 2 + 256;

    if (need > ws_size) {
        k_zero_f<<<(out_size + 255) / 256, 256, 0, stream>>>((float*)d_out, (size_t)out_size);
        k_diag<<<1, 64, 0, stream>>>((float*)d_out, (float)(ws_size >> 20));
        return;
    }

    char* w = (char*)d_ws;
    auto alloc = [&](size_t bytes) { char* p = w; w += (bytes + 255) & ~(size_t)255; return p; };
    char* r_acc = (char*)alloc(R_acc);
    char* r_msg = (char*)alloc(R_msg);
    char* r_al  = (char*)alloc(R_al);
    char* r_a1  = (char*)alloc(R_a1);
    unsigned short* Wt_i  = (unsigned short*)alloc(256 * 64 * 2);
    unsigned short* Wt_hi = (unsigned short*)alloc((size_t)256 * 320 * 2);
    unsigned short* Wt_o  = (unsigned short*)alloc((size_t)256 * 320 * 2);
    int* cnt_lg = (int*)alloc((size_t)E * 4);
    int* off_lg = (int*)alloc((size_t)E * 4);
    int* csr_lg = (int*)alloc((size_t)L * 4);
    int* cnt_nd = (int*)alloc((size_t)N * 4);
    int* off_nd = (int*)alloc((size_t)N * 4);
    int* csr_nd = (int*)alloc((size_t)E * 4);
    int* cnt_t  = (int*)alloc((size_t)N * 4);
    int* off_t  = (int*)alloc((size_t)N * 4);
    int* csr_t  = (int*)alloc((size_t)T * 4);
    int* gstart = (int*)alloc((size_t)G * 4);
    int* gcnt   = (int*)alloc((size_t)G * 4);
    int* cur    = (int*)alloc(256);

    unsigned char*  accum = (unsigned char*)r_acc;
    unsigned short* Mb    = (unsigned short*)r_acc;
    unsigned char*  msg   = (unsigned char*)r_msg;
    unsigned short* h     = (unsigned short*)r_msg;
    unsigned char*  alpha = (unsigned char*)r_al;
    unsigned char*  A1    = (unsigned char*)r_a1;
    unsigned char*  X1    = (unsigned char*)r_a1;

    // ---- init + CSR build (count -> offsets -> place) ----
    k_init<<<(E + 255) / 256, 256, 0, stream>>>(cnt_lg, E, cnt_nd, cnt_t, N, gcnt, gstart, G, cur);
    k_wt<<<320, 256, 0, stream>>>(W_i, W_h, W_o, Wt_i, Wt_hi, Wt_o);
    k_count<<<(L + 255) / 256, 256, 0, stream>>>(lg_dst, cnt_lg, L, edge_dst, cnt_nd, E,
                                                 tgt_nodes, cnt_t, T, graph_ids, gstart, gcnt, N);
    k_off<<<(E + 255) / 256, 256, 0, stream>>>(cnt_lg, off_lg, E, cnt_nd, off_nd, cnt_t, off_t, N, cur);
    k_place<<<(L + 255) / 256, 256, 0, stream>>>(lg_dst, lg_src, cnt_lg, off_lg, csr_lg, L,
                                                 edge_dst, cnt_nd, off_nd, csr_nd, E,
                                                 tgt_nodes, cnt_t, off_t, csr_t, T);
    k_alpha<<<(N + 3) / 4, 256, 0, stream>>>(tree_mess, cnt_t, off_t, csr_t, alpha, N);
    k_a1<<<(E * 4 + 255) / 256, 256, 0, stream>>>(node_x, bond_x, edge_src, A1, E);

    dim3 gE((E + 127) / 128, 1), gN((N + 127) / 128, 1);

    // msg0 = relu(A1 @ W_i)   [fp8 out]
    gemm4<0, 64, 0, false, true, true><<<gE, 256, 0, stream>>>(nullptr, 0, A1, 64, Wt_i, E, msg, nullptr);

    // 3 loopy-BP iters: accum = alpha[src] + gather(msg); msg = relu([accum|A1] @ Wt_hi^T)
    for (int it = 0; it < 3; ++it) {
        k_accum<<<(E + 15) / 16, 256, 0, stream>>>(msg, alpha, edge_src, cnt_lg, off_lg, csr_lg, accum, E);
        gemm4<256, 320, 0, true, true, true><<<gE, 256, 0, stream>>>(accum, 256, A1, 64, Wt_hi, E, msg, nullptr);
    }

    // final: Mb = alpha + node-gather(msg) [bf16]; X1 = node_x pad; h = relu([Mb|X1] @ Wt_o^T + b_o)
    k_x1<<<(N * 4 + 255) / 256, 256, 0, stream>>>(node_x, X1, N);                  // A1 dead
    k_mpa<<<(N + 15) / 16, 256, 0, stream>>>(msg, alpha, cnt_nd, off_nd, csr_nd, Mb, N); // accum dead
    gemm4<256, 320, 1, false, true, false><<<gN, 256, 0, stream>>>(Mb, 256, X1, 64, Wt_o, N, h, b_o); // msg dead
    k_gmean<<<G, 256, 0, stream>>>(h, gstart, gcnt, (float*)d_out, G);
}

// Round 10
// 763.264 us; speedup vs baseline: 1.1388x; 1.1388x over previous
//
#include <hip/hip_runtime.h>
#include <stdint.h>

#define HID 256
#define CAP 16

typedef __attribute__((ext_vector_type(8))) short bf16x8;   // 8 bf16 (4 VGPRs)
typedef __attribute__((ext_vector_type(4))) float f32x4;
typedef __attribute__((ext_vector_type(2))) float f32x2;

__device__ __forceinline__ float bf2f(unsigned short u) {
    union { unsigned int i; float f; } v; v.i = ((unsigned int)u) << 16; return v.f;
}
__device__ __forceinline__ unsigned short f2bf(float f) {
    union { float f; unsigned int i; } v; v.f = f;
    unsigned int r = (v.i + 0x7fffu + ((v.i >> 16) & 1u)) >> 16;
    return (unsigned short)r;
}
// ---- software fp8 e4m3fn fallbacks (exact w.r.t. the hw path) ----
__device__ __forceinline__ float fp82f_sw(unsigned char b) {
    unsigned int s = (unsigned int)(b & 0x80) << 24;
    int e = (b >> 3) & 0xF;
    int m = b & 7;
    float v;
    if (e) v = __uint_as_float(((unsigned int)(e + 120) << 23) | ((unsigned int)m << 20));
    else   v = (float)m * 0.001953125f;
    return __uint_as_float(__float_as_uint(v) | s);
}
__device__ __forceinline__ unsigned char f2fp8_sw(float x) {
    unsigned int bits = __float_as_uint(x);
    unsigned char s = (unsigned char)((bits >> 24) & 0x80);
    float ax = fabsf(x);
    if (!(ax >= 0.001953125f)) {
        int n = (int)rintf(ax * 512.f);
        return s | (unsigned char)n;
    }
    if (ax >= 448.f) return s | 0x7E;
    int ex; float mant = frexpf(ax, &ex);
    int e = ex + 6;
    if (e >= 1) {
        int q = (int)rintf(mant * 16.f);
        if (q == 16) { q = 8; ++e; }
        if (e > 15 || (e == 15 && q > 14)) return s | 0x7E;
        return s | (unsigned char)((e << 3) | (q - 8));
    } else {
        int n = (int)rintf(ax * 512.f);
        if (n >= 8) return s | 0x08;
        return s | (unsigned char)n;
    }
}
// ---- hardware fp8 conversion (gfx950: OCP e4m3fn) ----
__device__ __forceinline__ unsigned char f2fp8(float x) {
#if __has_builtin(__builtin_amdgcn_cvt_pk_fp8_f32)
    return (unsigned char)(__builtin_amdgcn_cvt_pk_fp8_f32(x, x, 0, false) & 0xff);
#else
    return f2fp8_sw(x);
#endif
}
__device__ __forceinline__ f32x4 fp8x4_to_f32(unsigned int u) {
#if __has_builtin(__builtin_amdgcn_cvt_pk_f32_fp8)
    f32x2 a = __builtin_amdgcn_cvt_pk_f32_fp8(u, false);
    f32x2 b = __builtin_amdgcn_cvt_pk_f32_fp8(u, true);
    f32x4 r; r[0] = a.x; r[1] = a.y; r[2] = b.x; r[3] = b.y;
    return r;
#else
    f32x4 r;
    #pragma unroll
    for (int q = 0; q < 4; ++q) r[q] = fp82f_sw((u >> (8 * q)) & 0xff);
    return r;
#endif
}
// 8 fp8 bytes -> 8 bf16 (exact: every e4m3fn value is representable in bf16)
__device__ __forceinline__ bf16x8 fp8x8_to_bf16x8(uint2 raw) {
#if __has_builtin(__builtin_amdgcn_cvt_pk_f32_fp8)
    f32x2 p0 = __builtin_amdgcn_cvt_pk_f32_fp8(raw.x, false);
    f32x2 p1 = __builtin_amdgcn_cvt_pk_f32_fp8(raw.x, true);
    f32x2 p2 = __builtin_amdgcn_cvt_pk_f32_fp8(raw.y, false);
    f32x2 p3 = __builtin_amdgcn_cvt_pk_f32_fp8(raw.y, true);
    union { unsigned int u[4]; bf16x8 v; } cv;
    cv.u[0] = (__float_as_uint(p0.x) >> 16) | (__float_as_uint(p0.y) & 0xffff0000u);
    cv.u[1] = (__float_as_uint(p1.x) >> 16) | (__float_as_uint(p1.y) & 0xffff0000u);
    cv.u[2] = (__float_as_uint(p2.x) >> 16) | (__float_as_uint(p2.y) & 0xffff0000u);
    cv.u[3] = (__float_as_uint(p3.x) >> 16) | (__float_as_uint(p3.y) & 0xffff0000u);
    return cv.v;
#else
    union { unsigned short u[8]; bf16x8 v; } cv;
    #pragma unroll
    for (int q = 0; q < 4; ++q) cv.u[q]     = f2bf(fp82f_sw((raw.x >> (8 * q)) & 0xff));
    #pragma unroll
    for (int q = 0; q < 4; ++q) cv.u[4 + q] = f2bf(fp82f_sw((raw.y >> (8 * q)) & 0xff));
    return cv.v;
#endif
}

// async global->LDS, 16B per lane; LDS dest = wave-uniform base + lane*16
__device__ __forceinline__ void llds16(const void* g, void* l) {
    __builtin_amdgcn_global_load_lds(
        (const __attribute__((address_space(1))) void*)g,
        (__attribute__((address_space(3))) void*)l, 16, 0, 0);
}

// ---------------- utility / prep kernels ----------------

__global__ void k_zero_f(float* __restrict__ p, size_t n) {
    size_t i = (size_t)blockIdx.x * 256 + threadIdx.x;
    if (i < n) p[i] = 0.f;
}
__global__ void k_diag(float* __restrict__ out, float v) {
    if (blockIdx.x == 0 && threadIdx.x == 0) out[0] = v;
}

// one-shot init: zero cnt_lg[E], cnt_nd[N], cnt_t[N]
__global__ void k_init(int* __restrict__ cnt_lg, int E,
                       int* __restrict__ cnt_nd, int* __restrict__ cnt_t, int N) {
    int i = blockIdx.x * 256 + threadIdx.x;
    if (i < E) cnt_lg[i] = 0;
    if (i < N) { cnt_nd[i] = 0; cnt_t[i] = 0; }
}

// merged bucket fills + atomic-free gstart boundary scan.
// graph_ids is SORTED -> gstart[g] derivable by boundary detection: at each i
// where gid[i-1] != gid[i], all g in (gid[i-1], gid[i]] start at i; the tail
// thread fills (gid[N-1], G] with N. Covers every g in [0, G] exactly once, so
// gstart needs no init and gcnt[g] = gstart[g+1] - gstart[g] (empty graphs -> 0).
__global__ void k_fills(const int* __restrict__ lg_dst, const int* __restrict__ lg_src,
                        int* __restrict__ cnt_lg, int* __restrict__ bkt_lg, int L,
                        const int* __restrict__ edst, int* __restrict__ cnt_nd,
                        int* __restrict__ bkt_nd, int E,
                        const int* __restrict__ tgt, int* __restrict__ cnt_t,
                        int* __restrict__ bkt_t, int T,
                        const int* __restrict__ gid, int* __restrict__ gstart, int N, int G) {
    int i = blockIdx.x * 256 + threadIdx.x;
    if (i < L) { int d = lg_dst[i]; int p = atomicAdd(&cnt_lg[d], 1); if (p < CAP) bkt_lg[(size_t)d * CAP + p] = lg_src[i]; }
    if (i < E) { int d = edst[i];   int p = atomicAdd(&cnt_nd[d], 1); if (p < CAP) bkt_nd[(size_t)d * CAP + p] = i; }
    if (i < T) { int d = tgt[i];    int p = atomicAdd(&cnt_t[d], 1);  if (p < CAP) bkt_t[(size_t)d * CAP + p] = i; }
    if (i < N) {
        int c = gid[i];
        int prev = (i == 0) ? -1 : gid[i - 1];
        for (int h = prev + 1; h <= c; ++h) gstart[h] = i;       // only boundary threads loop
        if (i == N - 1) { for (int h = c + 1; h <= G; ++h) gstart[h] = N; }
    }
}

// alpha[v] = fp8( sum_{t in bkt_t[v]} tree_mess[t] )   (one wave per node, 4 cols/lane)
__global__ void k_alpha(const float* __restrict__ tm, const int* __restrict__ cnt,
                        const int* __restrict__ bkt, unsigned char* __restrict__ alpha, int N) {
    int wave = threadIdx.x >> 6, lane = threadIdx.x & 63;
    int v = blockIdx.x * 4 + wave;
    if (v >= N) return;
    int d = cnt[v]; if (d > CAP) d = CAP;
    f32x4 s = {0.f, 0.f, 0.f, 0.f};
    const int* bb = bkt + (size_t)v * CAP;
    for (int t = 0; t < d; ++t) {
        int r = bb[t];
        f32x4 x = *(const f32x4*)(tm + (size_t)r * HID + lane * 4);
        #pragma unroll
        for (int k = 0; k < 4; ++k) s[k] += x[k];
    }
    union { unsigned char b[4]; unsigned int u; } ov;
    #pragma unroll
    for (int k = 0; k < 4; ++k) ov.b[k] = f2fp8(s[k]);
    *(unsigned int*)(alpha + (size_t)v * HID + lane * 4) = ov.u;
}

// merged weight builders (bf16, transposed+padded):
// Wt_i[n][k] (256x64): k<40 -> W_i[k][n]; Wt_hi[n][k] (256x320): k<256 W_h, k-256<40 W_i;
// Wt_o[n][k] (256x320): k<256 -> W_o[35+k][n], k-256<35 -> W_o[k-256][n]
__global__ void k_wt(const float* __restrict__ Wi, const float* __restrict__ Wh,
                     const float* __restrict__ Wo,
                     unsigned short* __restrict__ Wt_i, unsigned short* __restrict__ Wt_hi,
                     unsigned short* __restrict__ Wt_o) {
    int i = blockIdx.x * 256 + threadIdx.x;
    if (i < 256 * 64) {
        int n = i >> 6, k = i & 63;
        Wt_i[i] = f2bf((k < 40) ? Wi[k * HID + n] : 0.f);
    }
    if (i < 256 * 320) {
        int n = i / 320, k = i % 320;
        float v, u;
        if (k < 256) v = Wh[(size_t)k * HID + n];
        else if (k < 296) v = Wi[(size_t)(k - 256) * HID + n];
        else v = 0.f;
        Wt_hi[i] = f2bf(v);
        if (k < 256) u = Wo[(size_t)(35 + k) * HID + n];
        else if (k < 291) u = Wo[(size_t)(k - 256) * HID + n];
        else u = 0.f;
        Wt_o[i] = f2bf(u);
    }
}

// A1[e][0..63] fp8: k<35 node_x[src][k], 35..39 bond_x[e][k-35], else 0
// 4 threads/edge, 16B store each.
__global__ void k_a1(const float* __restrict__ nx, const float* __restrict__ bx,
                     const int* __restrict__ esrc, unsigned char* __restrict__ A1, int E) {
    int i = blockIdx.x * 256 + threadIdx.x;
    int e = i >> 2, q = i & 3;
    if (e >= E) return;
    int src = esrc[e];
    const float* row = nx + (size_t)src * 35;
    int base = q * 16;
    union { unsigned char b[16]; uint4 u; } ov;
    #pragma unroll
    for (int k = 0; k < 16; ++k) {
        int col = base + k;
        float v = 0.f;
        if (col < 35) v = row[col];
        else if (col < 40) v = bx[(size_t)e * 5 + (col - 35)];
        ov.b[k] = f2fp8(v);
    }
    *(uint4*)(A1 + (size_t)e * 64 + base) = ov.u;
}

// X1[v][0..63] fp8: k<35 node_x[v][k], else 0   (4 threads/node)
__global__ void k_x1(const float* __restrict__ nx, unsigned char* __restrict__ X1, int N) {
    int i = blockIdx.x * 256 + threadIdx.x;
    int v = i >> 2, q = i & 3;
    if (v >= N) return;
    const float* row = nx + (size_t)v * 35;
    int base = q * 16;
    union { unsigned char b[16]; uint4 u; } ov;
    #pragma unroll
    for (int k = 0; k < 16; ++k) {
        int col = base + k;
        ov.b[k] = f2fp8((col < 35) ? row[col] : 0.f);
    }
    *(uint4*)(X1 + (size_t)v * 64 + base) = ov.u;
}

// ---------------- split-A GEMM, m97 staging, 128x256 tile (R2 proven: ~80us) ----------------
// C[M,256] = [Ap (K1 cols) | Aq (KTOT-K1 cols)] @ B[256][KTOT]^T   (B bf16)
// BM=128, BN=256 (grid.y==1); 4 waves 2x2; per-wave 64x128; acc[4][8] f32x4.
// NOTE on occupancy (R7 lesson): gfx950 has a UNIFIED VGPR/AGPR file. This
// kernel's true register footprint is ~112 arch + 128 acc ≈ 240 regs/thread,
// so 2 waves/SIMD is the register-bound occupancy. __launch_bounds__(256,2)
// is the correct declaration; (256,4) caps the unified budget at 128 and
// spills the accumulators to scratch (405us, 944MB scratch writes — R7).
// Staging: global_load_lds width=16; source-chunk XOR swizzle both-sides
// (ck ^ (row&7) for 128B rows, ^(row&3) for 64B fp8 rows; same XOR on ds_read).
// fp8 A stays fp8 in LDS; converted to bf16 at fragment read.
// EPI 0: relu(C); EPI 1: relu(C + bias[col]).  OUTF8: store fp8 else bf16.
template<int K1, int KTOT, int EPI, bool PF8, bool QF8, bool OUTF8>
__global__ __launch_bounds__(256, 2)
void gemm4(const void* __restrict__ Ap, int lda1,
           const void* __restrict__ Aq, int lda2,
           const unsigned short* __restrict__ B, int M,
           void* __restrict__ out, const float* __restrict__ bias)
{
    constexpr int NKC = KTOT / 64;
    constexpr bool ABF = (K1 > 0 && !PF8) || (KTOT > K1 && !QF8);  // any bf16 A part
    __shared__ unsigned char Als[ABF ? 128 * 128 : 128 * 64];
    __shared__ unsigned char Bls[256 * 128];   // bf16 [256][128B]
    const int tid  = threadIdx.x;
    const int lane = tid & 63;
    const int wid  = tid >> 6;
    const int wm = wid & 1, wn = wid >> 1;
    const int row0 = blockIdx.x * 128;
    const int l15  = lane & 15;
    const int quad = lane >> 4;

    f32x4 acc[4][8] = {};

    // staging lane coords
    const int sA8_r = lane >> 2, sA8_c = lane & 3;   // fp8 A: 16 rows/issue, 4 chunks/row
    const int s16_r = lane >> 3, s16_c = lane & 7;   // 128B rows: 8 rows/issue, 8 chunks/row

    #pragma unroll
    for (int kc = 0; kc < NKC; ++kc) {
        const bool pPart = (kc * 64 < K1);
        const void* As = pPart ? Ap : Aq;
        const int  lda  = pPart ? lda1 : lda2;     // in elements of the A dtype
        const int  kofs = pPart ? kc * 64 : kc * 64 - K1;
        const bool f8   = pPart ? PF8 : QF8;

        // ---- stage A tile (async) ----
        if (f8) {
            #pragma unroll
            for (int t = 0; t < 2; ++t) {
                int r = wid * 32 + t * 16 + sA8_r;            // 0..127
                int ar = row0 + r; if (ar > M - 1) ar = M - 1;
                int ck = sA8_c ^ (r & 3);                      // source chunk (16B units)
                const unsigned char* g = (const unsigned char*)As + (size_t)ar * lda + kofs + ck * 16;
                llds16(g, &Als[(wid * 32 + t * 16) * 64]);
            }
        } else {
            #pragma unroll
            for (int t = 0; t < 4; ++t) {
                int r = wid * 32 + t * 8 + s16_r;
                int ar = row0 + r; if (ar > M - 1) ar = M - 1;
                int ck = s16_c ^ (r & 7);
                const unsigned char* g = (const unsigned char*)As + ((size_t)ar * lda + kofs) * 2 + ck * 16;
                llds16(g, &Als[(wid * 32 + t * 8) * 128]);
            }
        }
        // ---- stage B tile (async): all 256 rows of B[256][KTOT] ----
        #pragma unroll
        for (int t = 0; t < 8; ++t) {
            int r = wid * 64 + t * 8 + s16_r;                  // 0..255
            int ck = s16_c ^ (r & 7);
            const unsigned char* g = (const unsigned char*)B + ((size_t)r * KTOT + kc * 64) * 2 + ck * 16;
            llds16(g, &Bls[(wid * 64 + t * 8) * 128]);
        }
        __syncthreads();   // vmcnt drain before s_barrier -> tile resident

        // ---- MFMA phase ----
        #pragma unroll
        for (int kk = 0; kk < 64; kk += 32) {
            bf16x8 af[4];
            #pragma unroll
            for (int i = 0; i < 4; ++i) {
                int arow = wm * 64 + i * 16 + l15;
                if (f8) {
                    int ck = (kk >> 4) + (quad >> 1);          // 0..3
                    uint2 raw = *(const uint2*)&Als[arow * 64 + ((ck ^ (arow & 3)) << 4) + ((quad & 1) << 3)];
                    af[i] = fp8x8_to_bf16x8(raw);
                } else {
                    int ck = (kk >> 3) + quad;                 // 0..7
                    af[i] = *(const bf16x8*)&Als[arow * 128 + ((ck ^ (arow & 7)) << 4)];
                }
            }
            #pragma unroll
            for (int j = 0; j < 8; ++j) {
                int brow = wn * 128 + j * 16 + l15;
                int ck = (kk >> 3) + quad;
                bf16x8 bfr = *(const bf16x8*)&Bls[brow * 128 + ((ck ^ (brow & 7)) << 4)];
                #pragma unroll
                for (int i = 0; i < 4; ++i)
                    acc[i][j] = __builtin_amdgcn_mfma_f32_16x16x32_bf16(af[i], bfr, acc[i][j], 0, 0, 0);
            }
        }
        if (kc + 1 < NKC) __syncthreads();   // protect LDS before next stage
    }

    // epilogue: C/D layout col = lane&15, row = quad*4 + reg
    #pragma unroll
    for (int i = 0; i < 4; ++i) {
        int rbase = row0 + wm * 64 + i * 16 + quad * 4;
        #pragma unroll
        for (int r = 0; r < 4; ++r) {
            int row = rbase + r;
            if (row >= M) continue;
            #pragma unroll
            for (int j = 0; j < 8; ++j) {
                int col = wn * 128 + j * 16 + l15;
                float v = acc[i][j][r];
                if (EPI == 1) v += bias[col];
                v = v > 0.f ? v : 0.f;
                if (OUTF8) ((unsigned char*)out)[(size_t)row * HID + col] = f2fp8(v);
                else       ((unsigned short*)out)[(size_t)row * HID + col] = f2bf(v);
            }
        }
    }
}

// ---------------- gather kernels ----------------

// accum[e] = alpha[esrc[e]] + sum_{j in bkt[e]} msg[j]   (fp8 out)
// 4 edges per wave: 16 lanes x 16B per edge row (uint4), high-occupancy TLP.
__global__ void k_accum(const unsigned char* __restrict__ msg, const unsigned char* __restrict__ alpha,
                        const int* __restrict__ esrc, const int* __restrict__ cnt,
                        const int* __restrict__ bkt, unsigned char* __restrict__ accum, int E)
{
    int tid  = threadIdx.x;
    int lane = tid & 63, wave = tid >> 6;
    int sub  = lane >> 4;            // 0..3: which edge in this wave
    int sl   = lane & 15;
    int e = blockIdx.x * 16 + wave * 4 + sub;
    if (e >= E) return;
    int c = sl * 16;
    int src = esrc[e];
    int d = cnt[e]; if (d > CAP) d = CAP;
    uint4 au = *(const uint4*)(alpha + (size_t)src * HID + c);
    f32x4 s0 = fp8x4_to_f32(au.x);
    f32x4 s1 = fp8x4_to_f32(au.y);
    f32x4 s2 = fp8x4_to_f32(au.z);
    f32x4 s3 = fp8x4_to_f32(au.w);
    const int* bb = bkt + (size_t)e * CAP;
    for (int base = 0; base < d; base += 4) {
        int4 bi = *(const int4*)(bb + base);
        int rem = d - base;
        int i0 = bi.x;
        int i1 = (rem > 1) ? bi.y : bi.x;
        int i2 = (rem > 2) ? bi.z : bi.x;
        int i3 = (rem > 3) ? bi.w : bi.x;
        uint4 m0 = *(const uint4*)(msg + (size_t)i0 * HID + c);
        uint4 m1 = *(const uint4*)(msg + (size_t)i1 * HID + c);
        uint4 m2 = *(const uint4*)(msg + (size_t)i2 * HID + c);
        uint4 m3 = *(const uint4*)(msg + (size_t)i3 * HID + c);
        {   f32x4 a0 = fp8x4_to_f32(m0.x), a1 = fp8x4_to_f32(m0.y), a2 = fp8x4_to_f32(m0.z), a3 = fp8x4_to_f32(m0.w);
            #pragma unroll
            for (int k = 0; k < 4; ++k) { s0[k] += a0[k]; s1[k] += a1[k]; s2[k] += a2[k]; s3[k] += a3[k]; } }
        if (rem > 1) { f32x4 a0 = fp8x4_to_f32(m1.x), a1 = fp8x4_to_f32(m1.y), a2 = fp8x4_to_f32(m1.z), a3 = fp8x4_to_f32(m1.w);
            #pragma unroll
            for (int k = 0; k < 4; ++k) { s0[k] += a0[k]; s1[k] += a1[k]; s2[k] += a2[k]; s3[k] += a3[k]; } }
        if (rem > 2) { f32x4 a0 = fp8x4_to_f32(m2.x), a1 = fp8x4_to_f32(m2.y), a2 = fp8x4_to_f32(m2.z), a3 = fp8x4_to_f32(m2.w);
            #pragma unroll
            for (int k = 0; k < 4; ++k) { s0[k] += a0[k]; s1[k] += a1[k]; s2[k] += a2[k]; s3[k] += a3[k]; } }
        if (rem > 3) { f32x4 a0 = fp8x4_to_f32(m3.x), a1 = fp8x4_to_f32(m3.y), a2 = fp8x4_to_f32(m3.z), a3 = fp8x4_to_f32(m3.w);
            #pragma unroll
            for (int k = 0; k < 4; ++k) { s0[k] += a0[k]; s1[k] += a1[k]; s2[k] += a2[k]; s3[k] += a3[k]; } }
    }
    union { unsigned char b[16]; uint4 u; } ov;
    #pragma unroll
    for (int k = 0; k < 4; ++k) {
        ov.b[k]      = f2fp8(s0[k]);
        ov.b[4 + k]  = f2fp8(s1[k]);
        ov.b[8 + k]  = f2fp8(s2[k]);
        ov.b[12 + k] = f2fp8(s3[k]);
    }
    *(uint4*)(accum + (size_t)e * HID + c) = ov.u;
}

// Mb[v] = alpha[v] + sum_{e in bkt_nd[v]} msg[e]   (bf16 out)
// 4 nodes/wave: 16 lanes x 16 cols each (16B fp8 in, 32B bf16 out).
__global__ void k_mpa(const unsigned char* __restrict__ msg, const unsigned char* __restrict__ alpha,
                      const int* __restrict__ cnt, const int* __restrict__ bkt,
                      unsigned short* __restrict__ Mb, int N)
{
    int tid  = threadIdx.x;
    int lane = tid & 63, wave = tid >> 6;
    int sub  = lane >> 4;
    int sl   = lane & 15;
    int v = blockIdx.x * 16 + wave * 4 + sub;
    if (v >= N) return;
    int c = sl * 16;
    int d = cnt[v]; if (d > CAP) d = CAP;
    uint4 au = *(const uint4*)(alpha + (size_t)v * HID + c);
    f32x4 s0 = fp8x4_to_f32(au.x);
    f32x4 s1 = fp8x4_to_f32(au.y);
    f32x4 s2 = fp8x4_to_f32(au.z);
    f32x4 s3 = fp8x4_to_f32(au.w);
    const int* bb = bkt + (size_t)v * CAP;
    for (int base = 0; base < d; base += 4) {
        int4 bi = *(const int4*)(bb + base);
        int rem = d - base;
        int i0 = bi.x;
        int i1 = (rem > 1) ? bi.y : bi.x;
        int i2 = (rem > 2) ? bi.z : bi.x;
        int i3 = (rem > 3) ? bi.w : bi.x;
        uint4 m0 = *(const uint4*)(msg + (size_t)i0 * HID + c);
        uint4 m1 = *(const uint4*)(msg + (size_t)i1 * HID + c);
        uint4 m2 = *(const uint4*)(msg + (size_t)i2 * HID + c);
        uint4 m3 = *(const uint4*)(msg + (size_t)i3 * HID + c);
        {   f32x4 a0 = fp8x4_to_f32(m0.x), a1 = fp8x4_to_f32(m0.y), a2 = fp8x4_to_f32(m0.z), a3 = fp8x4_to_f32(m0.w);
            #pragma unroll
            for (int k = 0; k < 4; ++k) { s0[k] += a0[k]; s1[k] += a1[k]; s2[k] += a2[k]; s3[k] += a3[k]; } }
        if (rem > 1) { f32x4 a0 = fp8x4_to_f32(m1.x), a1 = fp8x4_to_f32(m1.y), a2 = fp8x4_to_f32(m1.z), a3 = fp8x4_to_f32(m1.w);
            #pragma unroll
            for (int k = 0; k < 4; ++k) { s0[k] += a0[k]; s1[k] += a1[k]; s2[k] += a2[k]; s3[k] += a3[k]; } }
        if (rem > 2) { f32x4 a0 = fp8x4_to_f32(m2.x), a1 = fp8x4_to_f32(m2.y), a2 = fp8x4_to_f32(m2.z), a3 = fp8x4_to_f32(m2.w);
            #pragma unroll
            for (int k = 0; k < 4; ++k) { s0[k] += a0[k]; s1[k] += a1[k]; s2[k] += a2[k]; s3[k] += a3[k]; } }
        if (rem > 3) { f32x4 a0 = fp8x4_to_f32(m3.x), a1 = fp8x4_to_f32(m3.y), a2 = fp8x4_to_f32(m3.z), a3 = fp8x4_to_f32(m3.w);
            #pragma unroll
            for (int k = 0; k < 4; ++k) { s0[k] += a0[k]; s1[k] += a1[k]; s2[k] += a2[k]; s3[k] += a3[k]; } }
    }
    union { unsigned short h[8]; uint4 u; } o1, o2;
    #pragma unroll
    for (int k = 0; k < 4; ++k) {
        o1.h[k] = f2bf(s0[k]); o1.h[4 + k] = f2bf(s1[k]);
        o2.h[k] = f2bf(s2[k]); o2.h[4 + k] = f2bf(s3[k]);
    }
    *(uint4*)(Mb + (size_t)v * HID + c)     = o1.u;
    *(uint4*)(Mb + (size_t)v * HID + c + 8) = o2.u;
}

// per-graph mean (graph_ids sorted -> contiguous rows), counts from gstart diffs
__global__ void k_gmean(const unsigned short* __restrict__ h, const int* __restrict__ gstart,
                        float* __restrict__ out, int G) {
    int g = blockIdx.x;
    int c = threadIdx.x;
    int st = gstart[g], n = gstart[g + 1] - st;
    float s0 = 0.f, s1 = 0.f, s2 = 0.f, s3 = 0.f;
    int r = 0;
    for (; r + 4 <= n; r += 4) {
        s0 += bf2f(h[(size_t)(st + r) * HID + c]);
        s1 += bf2f(h[(size_t)(st + r + 1) * HID + c]);
        s2 += bf2f(h[(size_t)(st + r + 2) * HID + c]);
        s3 += bf2f(h[(size_t)(st + r + 3) * HID + c]);
    }
    float s = (s0 + s1) + (s2 + s3);
    for (; r < n; ++r) s += bf2f(h[(size_t)(st + r) * HID + c]);
    out[(size_t)g * HID + c] = (n > 0) ? s / (float)n : 0.f;
}

// ---------------- launch ----------------
extern "C" void kernel_launch(void* const* d_in, const int* in_sizes, int n_in,
                              void* d_out, int out_size, void* d_ws, size_t ws_size,
                              hipStream_t stream)
{
    const float* node_x    = (const float*)d_in[0];
    const float* bond_x    = (const float*)d_in[1];
    const float* tree_mess = (const float*)d_in[2];
    const float* W_i       = (const float*)d_in[3];
    const float* W_h       = (const float*)d_in[4];
    const float* W_o       = (const float*)d_in[5];
    const float* b_o       = (const float*)d_in[6];
    const int* edge_src    = (const int*)d_in[7];
    const int* edge_dst    = (const int*)d_in[8];
    const int* lg_src      = (const int*)d_in[9];
    const int* lg_dst      = (const int*)d_in[10];
    const int* tgt_nodes   = (const int*)d_in[11];
    const int* graph_ids   = (const int*)d_in[12];

    const int N = in_sizes[0] / 35;
    const int E = in_sizes[1] / 5;
    const int T = in_sizes[2] / HID;
    const int L = in_sizes[9];
    const int G = out_size / HID;

    auto rup = [](size_t b) { return (b + 255) & ~(size_t)255; };
    const size_t szAcc = (size_t)E * HID;        // accum fp8
    const size_t szMsg = (size_t)E * HID;        // msg fp8
    const size_t szMbN = (size_t)N * HID * 2;    // Mb/h bf16
    const size_t R_acc = rup(szAcc > szMbN ? szAcc : szMbN);
    const size_t R_msg = rup(szMsg > szMbN ? szMsg : szMbN);
    const size_t R_al  = rup((size_t)N * HID);   // alpha fp8
    const size_t R_a1  = rup((size_t)E * 64);    // A1/X1 fp8
    const size_t need = R_acc + R_msg + R_al + R_a1
        + rup(256 * 64 * 2) + rup((size_t)256 * 320 * 2) * 2
        + rup((size_t)E * 4) + rup((size_t)E * CAP * 4)
        + rup((size_t)N * 4) + rup((size_t)N * CAP * 4)
        + rup((size_t)N * 4) + rup((size_t)N * CAP * 4)
        + rup((size_t)(G + 1) * 4);

    if (need > ws_size) {
        k_zero_f<<<(out_size + 255) / 256, 256, 0, stream>>>((float*)d_out, (size_t)out_size);
        k_diag<<<1, 64, 0, stream>>>((float*)d_out, (float)(ws_size >> 20));
        return;
    }

    char* w = (char*)d_ws;
    auto alloc = [&](size_t bytes) { char* p = w; w += (bytes + 255) & ~(size_t)255; return p; };
    char* r_acc = (char*)alloc(R_acc);
    char* r_msg = (char*)alloc(R_msg);
    char* r_al  = (char*)alloc(R_al);
    char* r_a1  = (char*)alloc(R_a1);
    unsigned short* Wt_i  = (unsigned short*)alloc(256 * 64 * 2);
    unsigned short* Wt_hi = (unsigned short*)alloc((size_t)256 * 320 * 2);
    unsigned short* Wt_o  = (unsigned short*)alloc((size_t)256 * 320 * 2);
    int* cnt_lg = (int*)alloc((size_t)E * 4);
    int* bkt_lg = (int*)alloc((size_t)E * CAP * 4);
    int* cnt_nd = (int*)alloc((size_t)N * 4);
    int* bkt_nd = (int*)alloc((size_t)N * CAP * 4);
    int* cnt_t  = (int*)alloc((size_t)N * 4);
    int* bkt_t  = (int*)alloc((size_t)N * CAP * 4);
    int* gstart = (int*)alloc((size_t)(G + 1) * 4);

    unsigned char*  accum = (unsigned char*)r_acc;
    unsigned short* Mb    = (unsigned short*)r_acc;
    unsigned char*  msg   = (unsigned char*)r_msg;
    unsigned short* h     = (unsigned short*)r_msg;
    unsigned char*  alpha = (unsigned char*)r_al;
    unsigned char*  A1    = (unsigned char*)r_a1;
    unsigned char*  X1    = (unsigned char*)r_a1;

    // ---- init + buckets (merged launches; gstart atomic-free via sorted gid) ----
    k_init<<<(E + 255) / 256, 256, 0, stream>>>(cnt_lg, E, cnt_nd, cnt_t, N);
    k_wt<<<320, 256, 0, stream>>>(W_i, W_h, W_o, Wt_i, Wt_hi, Wt_o);
    k_fills<<<(L + 255) / 256, 256, 0, stream>>>(lg_dst, lg_src, cnt_lg, bkt_lg, L,
                                                 edge_dst, cnt_nd, bkt_nd, E,
                                                 tgt_nodes, cnt_t, bkt_t, T,
                                                 graph_ids, gstart, N, G);
    k_alpha<<<(N + 3) / 4, 256, 0, stream>>>(tree_mess, cnt_t, bkt_t, alpha, N);
    k_a1<<<(E * 4 + 255) / 256, 256, 0, stream>>>(node_x, bond_x, edge_src, A1, E);

    dim3 gE((E + 127) / 128, 1), gN((N + 127) / 128, 1);

    // msg0 = relu(A1 @ W_i)   [fp8 out]
    gemm4<0, 64, 0, false, true, true><<<gE, 256, 0, stream>>>(nullptr, 0, A1, 64, Wt_i, E, msg, nullptr);

    // 3 loopy-BP iters: accum = alpha[src] + gather(msg); msg = relu([accum|A1] @ Wt_hi^T)
    for (int it = 0; it < 3; ++it) {
        k_accum<<<(E + 15) / 16, 256, 0, stream>>>(msg, alpha, edge_src, cnt_lg, bkt_lg, accum, E);
        gemm4<256, 320, 0, true, true, true><<<gE, 256, 0, stream>>>(accum, 256, A1, 64, Wt_hi, E, msg, nullptr);
    }

    // final: Mb = alpha + node-gather(msg) [bf16]; X1 = node_x pad; h = relu([Mb|X1] @ Wt_o^T + b_o)
    k_x1<<<(N * 4 + 255) / 256, 256, 0, stream>>>(node_x, X1, N);                  // A1 dead
    k_mpa<<<(N + 15) / 16, 256, 0, stream>>>(msg, alpha, cnt_nd, bkt_nd, Mb, N);   // accum dead
    gemm4<256, 320, 1, false, true, false><<<gN, 256, 0, stream>>>(Mb, 256, X1, 64, Wt_o, N, h, b_o); // msg dead
    k_gmean<<<G, 256, 0, stream>>>(h, gstart, (float*)d_out, G);
}